// Round 16
// baseline (314.897 us; speedup 1.0000x reference)
//
#include <hip/hip_runtime.h>
#include <hip/hip_bf16.h>
#include <stdint.h>

// Problem constants (reference: N=20000, E=640000, C=D=M=128)
#define DIM 128
#define HSTR 136    // padded LDS row stride in fp16 elems (272 B, 16B-aligned rows)
#define NMAX 20224  // LDS-staged scan capacity

using hfrag = __attribute__((ext_vector_type(8))) _Float16;  // 8 fp16 (4 VGPRs)
using h2v   = __attribute__((ext_vector_type(2))) _Float16;
using f32x4 = __attribute__((ext_vector_type(4))) float;     // MFMA C/D
using f32x2 = __attribute__((ext_vector_type(2))) float;

__device__ __forceinline__ float prelu_f(float v, float a) { return v >= 0.f ? v : a * v; }

// pack 2 floats -> fp16x2 (RTZ, 1 inst). Builtin returns __fp16x2; bitcast.
__device__ __forceinline__ unsigned pkh(float a, float b) {
    auto h = __builtin_amdgcn_cvt_pkrtz(a, b);
    return *(unsigned*)&h;
}
// packed fp16 prelu of (s+g): min(h,0)*a + max(h,0)
__device__ __forceinline__ unsigned prelu2_add(unsigned su, unsigned gu, h2v a2) {
    h2v s = *(h2v*)&su, g = *(h2v*)&gu;
    h2v h = s + g;
    h2v z = {(_Float16)0.f, (_Float16)0.f};
    h2v mx = __builtin_elementwise_max(h, z);
    h2v mn = __builtin_elementwise_min(h, z);
    h2v r = mn * a2 + mx;
    return *(unsigned*)&r;
}

// ---------------------------------------------------------------------------
// Merged prep + hist. Wall[m][n][k] = fp16(W_m[k][n]).
// ---------------------------------------------------------------------------
__global__ __launch_bounds__(256) void prep_hist_k(
    const float* __restrict__ Wsrc, const float* __restrict__ Wtgt,
    const float* __restrict__ Wskip, const float* __restrict__ W1,
    const float* __restrict__ W2, const float* __restrict__ b2,
    const float* __restrict__ Wg,
    unsigned short* __restrict__ Wall, float* __restrict__ w2g,
    const int* __restrict__ eidx, int E, int* __restrict__ deg)
{
    const int nhist = (E + 255) / 256;
    if ((int)blockIdx.x < nhist) {
        const int e = blockIdx.x * 256 + threadIdx.x;
        if (e < E) atomicAdd(deg + eidx[(size_t)E + e], 1);
        return;
    }
    const int b = blockIdx.x - nhist;
    if (b == (5 * DIM * DIM) / 256) {   // w2g block
        const int k = threadIdx.x;
        if (k < DIM) {
            float s = 0.f;
            for (int d = 0; d < DIM; ++d) s += W2[k * DIM + d] * Wg[d];
            w2g[k] = s;
        } else if (k == DIM) {
            float s = 0.f;
            for (int d = 0; d < DIM; ++d) s += b2[d] * Wg[d];
            w2g[DIM] = s;
        }
        return;
    }
    const int idx = b * 256 + threadIdx.x;
    const int m = idx >> 14;
    const int r = idx & 16383;
    const int n = r >> 7, k = r & 127;
    const float* W = (m == 0) ? Wsrc : (m == 1) ? Wtgt : (m == 2) ? Wskip : (m == 3) ? W1 : W2;
    const _Float16 hv = (_Float16)W[k * DIM + n];   // RNE scalar cvt
    Wall[idx] = *(const unsigned short*)&hv;
}

// ---------------------------------------------------------------------------
// Single-block scan, LDS-staged.
// ---------------------------------------------------------------------------
__global__ __launch_bounds__(256) void scan_k(const int* __restrict__ deg,
                                              int* __restrict__ rowptr,
                                              int* __restrict__ cursor, int N)
{
    __shared__ int part[256];
    const int t = threadIdx.x;

    if (N <= NMAX) {
        __shared__ int s[NMAX];
        for (int k = t; k < N; k += 256) s[k] = deg[k];
        __syncthreads();

        const int chunk = (N + 255) / 256;
        const int lo = min(t * chunk, N), hi = min(lo + chunk, N);
        int sum = 0;
        for (int k = lo; k < hi; ++k) sum += s[k];
        part[t] = sum;
        __syncthreads();
        for (int off = 1; off < 256; off <<= 1) {
            int u = (t >= off) ? part[t - off] : 0;
            __syncthreads();
            part[t] += u;
            __syncthreads();
        }
        int run = part[t] - sum;
        for (int k = lo; k < hi; ++k) { const int d = s[k]; s[k] = run; run += d; }
        __syncthreads();
        for (int k = t; k < N; k += 256) {
            const int v = s[k];
            rowptr[k] = v;
            cursor[k] = v;
        }
        if (t == 0) rowptr[N] = part[255];
    } else {
        const int chunk = (N + 255) / 256;
        const int lo = min(t * chunk, N), hi = min(lo + chunk, N);
        int s = 0;
        for (int k = lo; k < hi; ++k) s += deg[k];
        part[t] = s;
        __syncthreads();
        for (int off = 1; off < 256; off <<= 1) {
            int u = (t >= off) ? part[t - off] : 0;
            __syncthreads();
            part[t] += u;
            __syncthreads();
        }
        int run = part[t] - s;
        for (int k = lo; k < hi; ++k) {
            rowptr[k] = run;
            cursor[k] = run;
            run += deg[k];
        }
        if (t == 255) rowptr[N] = part[255];
    }
}

// ---------------------------------------------------------------------------
// Merged scatter + node_linear (fp16 msg outputs, fp16 MFMA).
// ---------------------------------------------------------------------------
__global__ __launch_bounds__(256) void scatter_node_k(
    const int* __restrict__ eidx, int E, int* __restrict__ cursor,
    int2* __restrict__ jip, int nscatter,
    const float* __restrict__ x,
    const unsigned short* __restrict__ Wall,
    const float* __restrict__ bsrc,
    unsigned short* __restrict__ msg_src, unsigned short* __restrict__ msg_tgt,
    float* __restrict__ skip, int N)
{
    if ((int)blockIdx.x < nscatter) {
        const int e = blockIdx.x * 256 + threadIdx.x;
        if (e < E) {
            const int j = eidx[e];
            const int i = eidx[(size_t)E + e];
            const int p = atomicAdd(cursor + i, 1);
            jip[p] = make_int2(j, i);
        }
        return;
    }

    __shared__ unsigned short xt[32 * HSTR];
    const int t = threadIdx.x;
    const int n0blk = (blockIdx.x - nscatter) * 32;
    const int w = t >> 6, lane = t & 63, col = lane & 15, quad = lane >> 4;

    for (int k = t; k < 32 * 16; k += 256) {
        const int row = k >> 4, o = k & 15;
        uint4 v = make_uint4(0, 0, 0, 0);
        if (n0blk + row < N) {
            const float4 a = *(const float4*)(x + (size_t)(n0blk + row) * DIM + o * 8);
            const float4 b = *(const float4*)(x + (size_t)(n0blk + row) * DIM + o * 8 + 4);
            v.x = pkh(a.x, a.y); v.y = pkh(a.z, a.w);
            v.z = pkh(b.x, b.y); v.w = pkh(b.z, b.w);
        }
        *(uint4*)(xt + row * HSTR + o * 8) = v;
    }
    __syncthreads();

    hfrag af[2][4];
    #pragma unroll
    for (int mt = 0; mt < 2; ++mt)
        #pragma unroll
        for (int ks = 0; ks < 4; ++ks)
            af[mt][ks] = *(const hfrag*)(xt + (mt * 16 + col) * HSTR + ks * 32 + quad * 8);

    for (int m = 0; m < 3; ++m) {
        const unsigned short* Wt = Wall + m * DIM * DIM;
        hfrag bw[2][4];
        #pragma unroll
        for (int nt = 0; nt < 2; ++nt)
            #pragma unroll
            for (int ks = 0; ks < 4; ++ks)
                bw[nt][ks] = *(const hfrag*)(Wt + (w * 32 + nt * 16 + col) * DIM + ks * 32 + quad * 8);

        f32x4 acc[2][2];
        #pragma unroll
        for (int mt = 0; mt < 2; ++mt)
            #pragma unroll
            for (int nt = 0; nt < 2; ++nt)
                acc[mt][nt] = f32x4{0.f, 0.f, 0.f, 0.f};

        #pragma unroll
        for (int mt = 0; mt < 2; ++mt)
            #pragma unroll
            for (int nt = 0; nt < 2; ++nt)
                #pragma unroll
                for (int ks = 0; ks < 4; ++ks)
                    acc[mt][nt] = __builtin_amdgcn_mfma_f32_16x16x32_f16(
                        bw[nt][ks], af[mt][ks], acc[mt][nt], 0, 0, 0);

        #pragma unroll
        for (int mt = 0; mt < 2; ++mt) {
            const int node = n0blk + mt * 16 + col;
            if (node >= N) continue;
            #pragma unroll
            for (int nt = 0; nt < 2; ++nt) {
                const int f0 = w * 32 + nt * 16 + quad * 4;
                if (m == 2) {
                    float4 o;
                    o.x = acc[mt][nt][0]; o.y = acc[mt][nt][1];
                    o.z = acc[mt][nt][2]; o.w = acc[mt][nt][3];
                    *(float4*)(skip + (size_t)node * DIM + f0) = o;
                } else {
                    float b0 = 0.f, b1v = 0.f, b2v = 0.f, b3v = 0.f;
                    if (m == 0) {
                        const float4 bb = *(const float4*)(bsrc + f0);
                        b0 = bb.x; b1v = bb.y; b2v = bb.z; b3v = bb.w;
                    }
                    uint2 o;
                    o.x = pkh(acc[mt][nt][0] + b0, acc[mt][nt][1] + b1v);
                    o.y = pkh(acc[mt][nt][2] + b2v, acc[mt][nt][3] + b3v);
                    unsigned short* dst = (m == 0) ? msg_src : msg_tgt;
                    *(uint2*)(dst + (size_t)node * DIM + f0) = o;
                }
            }
        }
    }
}

// ---------------------------------------------------------------------------
// K2: persistent, software-pipelined per-edge GEMM1 + gate over a tile
// sub-range [tile_begin, tile_end). Both src AND tgt rows are prefetched one
// tile ahead (no load stall in the combine phase). fp8 e4m3 h2buf storage.
// ---------------------------------------------------------------------------
__global__ __launch_bounds__(256, 3) void edge_mlp_mfma(
    const int2* __restrict__ jip, int tile_begin, int tile_end,
    const unsigned short* __restrict__ msg_src, const unsigned short* __restrict__ msg_tgt,
    const float* __restrict__ a0p,
    const unsigned short* __restrict__ W1t, const float* __restrict__ b1,
    const float* __restrict__ a1p,
    const float* __restrict__ w2g,
    unsigned char* __restrict__ h2buf,      // fp8 e4m3 [E,128], perm order
    float* __restrict__ gate)
{
    __shared__ unsigned short h1[2][64 * HSTR];
    __shared__ float gate_part[2][4][64];

    const int t = threadIdx.x;
    const float a0 = *a0p, a1 = *a1p;
    const h2v a02 = {(_Float16)a0, (_Float16)a0};
    const int w = t >> 6, lane = t & 63, col = lane & 15, quad = lane >> 4;
    const int o = t & 15, r0 = t >> 4;

    hfrag bw1[2][4];
    float4 b1q[2], wgq[2];
    #pragma unroll
    for (int nt = 0; nt < 2; ++nt) {
        const int n = w * 32 + nt * 16 + col;
        #pragma unroll
        for (int ks = 0; ks < 4; ++ks)
            bw1[nt][ks] = *(const hfrag*)(W1t + n * DIM + ks * 32 + quad * 8);
        const int nq = w * 32 + nt * 16 + quad * 4;
        b1q[nt] = *(const float4*)(b1 + nq);
        wgq[nt] = *(const float4*)(w2g + nq);
    }
    const float c2 = w2g[DIM];
    const int stride = gridDim.x;

    int tile = tile_begin + blockIdx.x;
    if (tile >= tile_end) return;

    int2 eA[4], eB[4];
    uint4 svA[4], svB[4], gvA[4], gvB[4];

    {
        const int p0 = tile * 64;
        #pragma unroll
        for (int i = 0; i < 4; ++i) eA[i] = jip[p0 + r0 + 16 * i];
        #pragma unroll
        for (int i = 0; i < 4; ++i) {
            svA[i] = *(const uint4*)(msg_src + (size_t)eA[i].x * DIM + o * 8);
            gvA[i] = *(const uint4*)(msg_tgt + (size_t)eA[i].y * DIM + o * 8);
        }
        const int tn = tile + stride;
        const int p1 = (tn < tile_end ? tn : tile) * 64;
        #pragma unroll
        for (int i = 0; i < 4; ++i) eB[i] = jip[p1 + r0 + 16 * i];
    }

    int buf = 0;
    int prev_p0 = -1;

    for (; tile < tile_end; tile += stride) {
        const int p0 = tile * 64;

        // 1. issue NEXT tile's src + tgt loads (fly across this iteration)
        #pragma unroll
        for (int i = 0; i < 4; ++i) {
            svB[i] = *(const uint4*)(msg_src + (size_t)eB[i].x * DIM + o * 8);
            gvB[i] = *(const uint4*)(msg_tgt + (size_t)eB[i].y * DIM + o * 8);
        }

        // 2. combine current tile entirely from registers (no load stall)
        #pragma unroll
        for (int i = 0; i < 4; ++i) {
            uint4 hv;
            hv.x = prelu2_add(svA[i].x, gvA[i].x, a02);
            hv.y = prelu2_add(svA[i].y, gvA[i].y, a02);
            hv.z = prelu2_add(svA[i].z, gvA[i].z, a02);
            hv.w = prelu2_add(svA[i].w, gvA[i].w, a02);
            *(uint4*)(h1[buf] + (r0 + 16 * i) * HSTR + o * 8) = hv;
        }

        // 3. rotate idx; prefetch idx for tile+2*stride
        #pragma unroll
        for (int i = 0; i < 4; ++i) eA[i] = eB[i];
        {
            const int tnn = tile + 2 * stride;
            const int p2 = (tnn < tile_end ? tnn : tile) * 64;
            #pragma unroll
            for (int i = 0; i < 4; ++i) eB[i] = jip[p2 + r0 + 16 * i];
        }

        __syncthreads();

        // 3b. deferred gate write for PREVIOUS tile
        if (prev_p0 >= 0 && t < 64)
            gate[prev_p0 + t] = gate_part[1 - buf][0][t] + gate_part[1 - buf][1][t]
                              + gate_part[1 - buf][2][t] + gate_part[1 - buf][3][t] + c2;

        // 4. GEMM1 (transposed, fp16)
        f32x4 acc[4][2];
        #pragma unroll
        for (int mt = 0; mt < 4; ++mt)
            #pragma unroll
            for (int nt = 0; nt < 2; ++nt)
                acc[mt][nt] = f32x4{0.f, 0.f, 0.f, 0.f};

        #pragma unroll
        for (int mt = 0; mt < 4; ++mt) {
            hfrag af[4];
            #pragma unroll
            for (int ks = 0; ks < 4; ++ks)
                af[ks] = *(const hfrag*)(h1[buf] + (mt * 16 + col) * HSTR + ks * 32 + quad * 8);
            #pragma unroll
            for (int nt = 0; nt < 2; ++nt)
                #pragma unroll
                for (int ks = 0; ks < 4; ++ks)
                    acc[mt][nt] = __builtin_amdgcn_mfma_f32_16x16x32_f16(
                        bw1[nt][ks], af[ks], acc[mt][nt], 0, 0, 0);
        }

        // 5. epilogue: prelu -> h2buf (fp8), gate partials (fp32)
        #pragma unroll
        for (int mt = 0; mt < 4; ++mt) {
            const int m = mt * 16 + col;
            float g = 0.f;
            #pragma unroll
            for (int nt = 0; nt < 2; ++nt) {
                const int n0 = w * 32 + nt * 16 + quad * 4;
                const float p0v = prelu_f(acc[mt][nt][0] + b1q[nt].x, a1);
                const float p1v = prelu_f(acc[mt][nt][1] + b1q[nt].y, a1);
                const float p2v = prelu_f(acc[mt][nt][2] + b1q[nt].z, a1);
                const float p3v = prelu_f(acc[mt][nt][3] + b1q[nt].w, a1);
                int pk = __builtin_amdgcn_cvt_pk_fp8_f32(p0v, p1v, 0, false);
                pk = __builtin_amdgcn_cvt_pk_fp8_f32(p2v, p3v, pk, true);
                *(unsigned*)(h2buf + (size_t)(p0 + m) * DIM + n0) = (unsigned)pk;
                g += p0v * wgq[nt].x + p1v * wgq[nt].y + p2v * wgq[nt].z + p3v * wgq[nt].w;
            }
            g += __shfl_xor(g, 16);
            g += __shfl_xor(g, 32);
            if (quad == 0) gate_part[buf][w][m] = g;
        }

        // 6. rotate data registers
        #pragma unroll
        for (int i = 0; i < 4; ++i) { svA[i] = svB[i]; gvA[i] = gvB[i]; }
        prev_p0 = p0;
        buf ^= 1;
    }

    __syncthreads();
    if (t < 64)
        gate[prev_p0 + t] = gate_part[1 - buf][0][t] + gate_part[1 - buf][1][t]
                          + gate_part[1 - buf][2][t] + gate_part[1 - buf][3][t] + c2;
}

// ---------------------------------------------------------------------------
// K3: single-pass shift-free softmax aggregation over fp8 h2buf -> fp16 aggh2.
// ---------------------------------------------------------------------------
__global__ __launch_bounds__(256) void aggregate_h2_k(
    const int* __restrict__ rowptr,
    const float* __restrict__ gate, const unsigned char* __restrict__ h2buf,
    unsigned short* __restrict__ aggh2, int N)
{
    const int n = blockIdx.x * 4 + (threadIdx.x >> 6);
    const int lane = threadIdx.x & 63;
    if (n >= N) return;

    const int base = rowptr[n];
    const int deg = rowptr[n + 1] - base;
    const int grp = lane >> 4, sub = lane & 15;

    float acc[8] = {0.f, 0.f, 0.f, 0.f, 0.f, 0.f, 0.f, 0.f};
    float se = 0.f;
    for (int k = grp; k < deg; k += 4) {
        const float e = __expf(fminf(gate[base + k], 60.f));
        se += e;
        const uint2 mv = *(const uint2*)(h2buf + (size_t)(base + k) * DIM + sub * 8);
        const f32x2 f01 = __builtin_amdgcn_cvt_pk_f32_fp8(mv.x, false);
        const f32x2 f23 = __builtin_amdgcn_cvt_pk_f32_fp8(mv.x, true);
        const f32x2 f45 = __builtin_amdgcn_cvt_pk_f32_fp8(mv.y, false);
        const f32x2 f67 = __builtin_amdgcn_cvt_pk_f32_fp8(mv.y, true);
        acc[0] += e * f01.x; acc[1] += e * f01.y;
        acc[2] += e * f23.x; acc[3] += e * f23.y;
        acc[4] += e * f45.x; acc[5] += e * f45.y;
        acc[6] += e * f67.x; acc[7] += e * f67.y;
    }
    #pragma unroll
    for (int j = 0; j < 8; ++j) {
        acc[j] += __shfl_xor(acc[j], 16);
        acc[j] += __shfl_xor(acc[j], 32);
    }
    se += __shfl_xor(se, 16);
    se += __shfl_xor(se, 32);
    const float inv = 1.f / (se + 1e-16f);

    if (grp == 0) {
        uint4 ov;
        ov.x = pkh(acc[0] * inv, acc[1] * inv);
        ov.y = pkh(acc[2] * inv, acc[3] * inv);
        ov.z = pkh(acc[4] * inv, acc[5] * inv);
        ov.w = pkh(acc[6] * inv, acc[7] * inv);
        *(uint4*)(aggh2 + (size_t)n * DIM + sub * 8) = ov;
    }
}

// ---------------------------------------------------------------------------
// K4: out = LN(aggh2 @ W2 + b2 + skip) * gamma + beta, via fp16 MFMA.
// ---------------------------------------------------------------------------
__global__ __launch_bounds__(256) void node_out_k(
    const unsigned short* __restrict__ aggh2,
    const unsigned short* __restrict__ W2t, const float* __restrict__ b2,
    const float* __restrict__ skip,
    const float* __restrict__ gamma, const float* __restrict__ beta,
    float* __restrict__ out, int N)
{
    __shared__ unsigned short hh[64 * HSTR];
    __shared__ float ls1[4][4][16], ls2[4][4][16];

    const int t = threadIdx.x;
    const int n0blk = blockIdx.x * 64;
    const int w = t >> 6, lane = t & 63, col = lane & 15, quad = lane >> 4;

    hfrag bw2[2][4];
    float4 b2q[2];
    #pragma unroll
    for (int nt = 0; nt < 2; ++nt) {
        const int n = w * 32 + nt * 16 + col;
        #pragma unroll
        for (int ks = 0; ks < 4; ++ks)
            bw2[nt][ks] = *(const hfrag*)(W2t + n * DIM + ks * 32 + quad * 8);
        b2q[nt] = *(const float4*)(b2 + w * 32 + nt * 16 + quad * 4);
    }

    for (int k = t; k < 64 * 16; k += 256) {
        const int row = k >> 4, o = k & 15;
        uint4 v = make_uint4(0, 0, 0, 0);
        if (n0blk + row < N) v = *(const uint4*)(aggh2 + (size_t)(n0blk + row) * DIM + o * 8);
        *(uint4*)(hh + row * HSTR + o * 8) = v;
    }
    __syncthreads();

    f32x4 acc[4][2];
    #pragma unroll
    for (int mt = 0; mt < 4; ++mt)
        #pragma unroll
        for (int nt = 0; nt < 2; ++nt)
            acc[mt][nt] = f32x4{0.f, 0.f, 0.f, 0.f};

    #pragma unroll
    for (int mt = 0; mt < 4; ++mt) {
        hfrag af[4];
        #pragma unroll
        for (int ks = 0; ks < 4; ++ks)
            af[ks] = *(const hfrag*)(hh + (mt * 16 + col) * HSTR + ks * 32 + quad * 8);
        #pragma unroll
        for (int nt = 0; nt < 2; ++nt)
            #pragma unroll
            for (int ks = 0; ks < 4; ++ks)
                acc[mt][nt] = __builtin_amdgcn_mfma_f32_16x16x32_f16(
                    bw2[nt][ks], af[ks], acc[mt][nt], 0, 0, 0);
    }

    float v[4][2][4];
    #pragma unroll
    for (int mt = 0; mt < 4; ++mt) {
        const int node = n0blk + mt * 16 + col;
        float s1 = 0.f, s2 = 0.f;
        #pragma unroll
        for (int nt = 0; nt < 2; ++nt) {
            const int f0 = w * 32 + nt * 16 + quad * 4;
            float4 sk = make_float4(0.f, 0.f, 0.f, 0.f);
            if (node < N) sk = *(const float4*)(skip + (size_t)node * DIM + f0);
            v[mt][nt][0] = acc[mt][nt][0] + b2q[nt].x + sk.x;
            v[mt][nt][1] = acc[mt][nt][1] + b2q[nt].y + sk.y;
            v[mt][nt][2] = acc[mt][nt][2] + b2q[nt].z + sk.z;
            v[mt][nt][3] = acc[mt][nt][3] + b2q[nt].w + sk.w;
            #pragma unroll
            for (int r = 0; r < 4; ++r) {
                s1 += v[mt][nt][r];
                s2 += v[mt][nt][r] * v[mt][nt][r];
            }
        }
        s1 += __shfl_xor(s1, 16); s1 += __shfl_xor(s1, 32);
        s2 += __shfl_xor(s2, 16); s2 += __shfl_xor(s2, 32);
        if (quad == 0) { ls1[w][mt][col] = s1; ls2[w][mt][col] = s2; }
    }
    __syncthreads();

    #pragma unroll
    for (int mt = 0; mt < 4; ++mt) {
        const int node = n0blk + mt * 16 + col;
        if (node >= N) continue;
        const float sum = ls1[0][mt][col] + ls1[1][mt][col] + ls1[2][mt][col] + ls1[3][mt][col];
        const float sq  = ls2[0][mt][col] + ls2[1][mt][col] + ls2[2][mt][col] + ls2[3][mt][col];
        const float mu = sum * (1.f / 128.f);
        const float var = sq * (1.f / 128.f) - mu * mu;
        const float rs = rsqrtf(var + 1e-5f);
        #pragma unroll
        for (int nt = 0; nt < 2; ++nt) {
            const int f0 = w * 32 + nt * 16 + quad * 4;
            const float4 gm = *(const float4*)(gamma + f0);
            const float4 bt = *(const float4*)(beta + f0);
            float4 ov;
            ov.x = (v[mt][nt][0] - mu) * rs * gm.x + bt.x;
            ov.y = (v[mt][nt][1] - mu) * rs * gm.y + bt.y;
            ov.z = (v[mt][nt][2] - mu) * rs * gm.z + bt.z;
            ov.w = (v[mt][nt][3] - mu) * rs * gm.w + bt.w;
            *(float4*)(out + (size_t)node * DIM + f0) = ov;
        }
    }
}

// ---------------------------------------------------------------------------
extern "C" void kernel_launch(void* const* d_in, const int* in_sizes, int n_in,
                              void* d_out, int out_size, void* d_ws, size_t ws_size,
                              hipStream_t stream)
{
    const float* x     = (const float*)d_in[0];
    const int*   eidx  = (const int*)d_in[1];
    const float* Wsrc  = (const float*)d_in[2];
    const float* bsrc  = (const float*)d_in[3];
    const float* Wtgt  = (const float*)d_in[4];
    const float* Wskip = (const float*)d_in[5];
    const float* a0    = (const float*)d_in[6];
    const float* W1    = (const float*)d_in[7];
    const float* b1    = (const float*)d_in[8];
    const float* a1    = (const float*)d_in[9];
    const float* W2    = (const float*)d_in[10];
    const float* b2    = (const float*)d_in[11];
    const float* Wg    = (const float*)d_in[12];
    const float* gamma = (const float*)d_in[13];
    const float* beta  = (const float*)d_in[14];

    const int N = in_sizes[0] / DIM;      // 20000
    const int E = in_sizes[1] / 2;        // 640000
    const int Npad = ((N + 63) / 64) * 64;
    float* out = (float*)d_out;

    char* ws = (char*)d_ws;
    size_t off = 0;
    auto alloc = [&](size_t bytes) -> void* {
        void* p = ws + off;
        off += (bytes + 255) & ~(size_t)255;
        return p;
    };
    unsigned short* msg_src = (unsigned short*)alloc((size_t)N * DIM * 2);
    unsigned short* msg_tgt = (unsigned short*)alloc((size_t)N * DIM * 2);
    float*          skip    = (float*)alloc((size_t)N * DIM * 4);
    float*          gate    = (float*)alloc((size_t)E * 4);
    int*            deg     = (int*)alloc((size_t)N * 4);
    int*            rowptr  = (int*)alloc((size_t)(N + 1) * 4);
    int*            cursor  = (int*)alloc((size_t)N * 4);
    int2*           jip     = (int2*)alloc((size_t)E * 8);
    unsigned short* Wall    = (unsigned short*)alloc((size_t)5 * DIM * DIM * 2);
    float*          w2g     = (float*)alloc((size_t)(DIM + 1) * 4);
    unsigned short* aggh2   = (unsigned short*)alloc((size_t)Npad * DIM * 2);
    unsigned char*  h2buf   = (unsigned char*)alloc((size_t)E * DIM);
    (void)ws_size; (void)n_in; (void)out_size;

    (void)hipMemsetAsync(deg, 0, (size_t)N * 4, stream);

    const int nhist = (E + 255) / 256;
    prep_hist_k<<<nhist + (5 * DIM * DIM) / 256 + 1, 256, 0, stream>>>(
        Wsrc, Wtgt, Wskip, W1, W2, b2, Wg, Wall, w2g, eidx, E, deg);

    scan_k<<<1, 256, 0, stream>>>(deg, rowptr, cursor, N);

    const int nscatter = (E + 255) / 256;
    const int nnode = (N + 31) / 32;
    scatter_node_k<<<nscatter + nnode, 256, 0, stream>>>(
        eidx, E, cursor, jip, nscatter,
        x, Wall, bsrc, msg_src, msg_tgt, skip, N);

    // edge kernel split into 4 quarter-dispatches (diagnostic: lowers the
    // top-5 visibility threshold to ~19 us; work identical)
    const int ntiles = E / 64;
    const int nq = 4;
    for (int q = 0; q < nq; ++q) {
        const int tb = (int)(((long long)ntiles * q) / nq);
        const int te = (int)(((long long)ntiles * (q + 1)) / nq);
        const int span = te - tb;
        if (span <= 0) continue;
        const int egrid = span < 1024 ? span : 1024;
        edge_mlp_mfma<<<egrid, 256, 0, stream>>>(jip, tb, te, msg_src, msg_tgt, a0,
                                                 Wall + 3 * DIM * DIM, b1, a1,
                                                 w2g, h2buf, gate);
    }

    aggregate_h2_k<<<(N + 3) / 4, 256, 0, stream>>>(rowptr, gate, h2buf, aggh2, N);

    node_out_k<<<Npad / 64, 256, 0, stream>>>(aggh2, Wall + 4 * DIM * DIM, b2, skip,
                                              gamma, beta, out, N);
}

// Round 17
// 251.085 us; speedup vs baseline: 1.2541x; 1.2541x over previous
//
#include <hip/hip_runtime.h>
#include <hip/hip_bf16.h>
#include <stdint.h>

// Problem constants (reference: N=20000, E=640000, C=D=M=128)
#define DIM 128
#define HSTR 136    // padded LDS row stride in fp16 elems (272 B, 16B-aligned rows)
#define NMAX 20224  // LDS-staged scan capacity

using hfrag = __attribute__((ext_vector_type(8))) _Float16;  // 8 fp16 (4 VGPRs)
using h2v   = __attribute__((ext_vector_type(2))) _Float16;
using f32x4 = __attribute__((ext_vector_type(4))) float;     // MFMA C/D
using f32x2 = __attribute__((ext_vector_type(2))) float;

__device__ __forceinline__ float prelu_f(float v, float a) { return v >= 0.f ? v : a * v; }

// pack 2 floats -> fp16x2 (RTZ, 1 inst). Builtin returns __fp16x2; bitcast.
__device__ __forceinline__ unsigned pkh(float a, float b) {
    auto h = __builtin_amdgcn_cvt_pkrtz(a, b);
    return *(unsigned*)&h;
}
// packed fp16 prelu of (s+g): min(h,0)*a + max(h,0)
__device__ __forceinline__ unsigned prelu2_add(unsigned su, unsigned gu, h2v a2) {
    h2v s = *(h2v*)&su, g = *(h2v*)&gu;
    h2v h = s + g;
    h2v z = {(_Float16)0.f, (_Float16)0.f};
    h2v mx = __builtin_elementwise_max(h, z);
    h2v mn = __builtin_elementwise_min(h, z);
    h2v r = mn * a2 + mx;
    return *(unsigned*)&r;
}

// ---------------------------------------------------------------------------
// Merged prep + hist. Hist also captures per-edge rank (coalesced store),
// so the later scatter needs NO atomics. Wall[m][n][k] = fp16(W_m[k][n]).
// ---------------------------------------------------------------------------
__global__ __launch_bounds__(256) void prep_hist_k(
    const float* __restrict__ Wsrc, const float* __restrict__ Wtgt,
    const float* __restrict__ Wskip, const float* __restrict__ W1,
    const float* __restrict__ W2, const float* __restrict__ b2,
    const float* __restrict__ Wg,
    unsigned short* __restrict__ Wall, float* __restrict__ w2g,
    const int* __restrict__ eidx, int E, int* __restrict__ deg,
    int* __restrict__ rank)
{
    const int nhist = (E + 255) / 256;
    if ((int)blockIdx.x < nhist) {
        const int e = blockIdx.x * 256 + threadIdx.x;
        if (e < E) rank[e] = atomicAdd(deg + eidx[(size_t)E + e], 1);
        return;
    }
    const int b = blockIdx.x - nhist;
    if (b == (5 * DIM * DIM) / 256) {   // w2g block
        const int k = threadIdx.x;
        if (k < DIM) {
            float s = 0.f;
            for (int d = 0; d < DIM; ++d) s += W2[k * DIM + d] * Wg[d];
            w2g[k] = s;
        } else if (k == DIM) {
            float s = 0.f;
            for (int d = 0; d < DIM; ++d) s += b2[d] * Wg[d];
            w2g[DIM] = s;
        }
        return;
    }
    const int idx = b * 256 + threadIdx.x;
    const int m = idx >> 14;
    const int r = idx & 16383;
    const int n = r >> 7, k = r & 127;
    const float* W = (m == 0) ? Wsrc : (m == 1) ? Wtgt : (m == 2) ? Wskip : (m == 3) ? W1 : W2;
    const _Float16 hv = (_Float16)W[k * DIM + n];   // RNE scalar cvt
    Wall[idx] = *(const unsigned short*)&hv;
}

// ---------------------------------------------------------------------------
// Single-block scan, LDS-staged. rowptr only (scatter is atomic-free now).
// ---------------------------------------------------------------------------
__global__ __launch_bounds__(256) void scan_k(const int* __restrict__ deg,
                                              int* __restrict__ rowptr, int N)
{
    __shared__ int part[256];
    const int t = threadIdx.x;

    if (N <= NMAX) {
        __shared__ int s[NMAX];
        for (int k = t; k < N; k += 256) s[k] = deg[k];
        __syncthreads();

        const int chunk = (N + 255) / 256;
        const int lo = min(t * chunk, N), hi = min(lo + chunk, N);
        int sum = 0;
        for (int k = lo; k < hi; ++k) sum += s[k];
        part[t] = sum;
        __syncthreads();
        for (int off = 1; off < 256; off <<= 1) {
            int u = (t >= off) ? part[t - off] : 0;
            __syncthreads();
            part[t] += u;
            __syncthreads();
        }
        int run = part[t] - sum;
        for (int k = lo; k < hi; ++k) { const int d = s[k]; s[k] = run; run += d; }
        __syncthreads();
        for (int k = t; k < N; k += 256) rowptr[k] = s[k];
        if (t == 0) rowptr[N] = part[255];
    } else {
        const int chunk = (N + 255) / 256;
        const int lo = min(t * chunk, N), hi = min(lo + chunk, N);
        int s = 0;
        for (int k = lo; k < hi; ++k) s += deg[k];
        part[t] = s;
        __syncthreads();
        for (int off = 1; off < 256; off <<= 1) {
            int u = (t >= off) ? part[t - off] : 0;
            __syncthreads();
            part[t] += u;
            __syncthreads();
        }
        int run = part[t] - s;
        for (int k = lo; k < hi; ++k) {
            rowptr[k] = run;
            run += deg[k];
        }
        if (t == 255) rowptr[N] = part[255];
    }
}

// ---------------------------------------------------------------------------
// Merged scatter + node_linear. Scatter is atomic-free:
// p = rowptr[i] + rank[e] (rowptr L2-resident), fire-and-forget jip write.
// ---------------------------------------------------------------------------
__global__ __launch_bounds__(256) void scatter_node_k(
    const int* __restrict__ eidx, int E,
    const int* __restrict__ rowptr, const int* __restrict__ rank,
    int2* __restrict__ jip, int nscatter,
    const float* __restrict__ x,
    const unsigned short* __restrict__ Wall,
    const float* __restrict__ bsrc,
    unsigned short* __restrict__ msg_src, unsigned short* __restrict__ msg_tgt,
    float* __restrict__ skip, int N)
{
    if ((int)blockIdx.x < nscatter) {
        const int e = blockIdx.x * 256 + threadIdx.x;
        if (e < E) {
            const int j = eidx[e];
            const int i = eidx[(size_t)E + e];
            const int p = rowptr[i] + rank[e];
            jip[p] = make_int2(j, i);
        }
        return;
    }

    __shared__ unsigned short xt[32 * HSTR];
    const int t = threadIdx.x;
    const int n0blk = (blockIdx.x - nscatter) * 32;
    const int w = t >> 6, lane = t & 63, col = lane & 15, quad = lane >> 4;

    for (int k = t; k < 32 * 16; k += 256) {
        const int row = k >> 4, o = k & 15;
        uint4 v = make_uint4(0, 0, 0, 0);
        if (n0blk + row < N) {
            const float4 a = *(const float4*)(x + (size_t)(n0blk + row) * DIM + o * 8);
            const float4 b = *(const float4*)(x + (size_t)(n0blk + row) * DIM + o * 8 + 4);
            v.x = pkh(a.x, a.y); v.y = pkh(a.z, a.w);
            v.z = pkh(b.x, b.y); v.w = pkh(b.z, b.w);
        }
        *(uint4*)(xt + row * HSTR + o * 8) = v;
    }
    __syncthreads();

    hfrag af[2][4];
    #pragma unroll
    for (int mt = 0; mt < 2; ++mt)
        #pragma unroll
        for (int ks = 0; ks < 4; ++ks)
            af[mt][ks] = *(const hfrag*)(xt + (mt * 16 + col) * HSTR + ks * 32 + quad * 8);

    for (int m = 0; m < 3; ++m) {
        const unsigned short* Wt = Wall + m * DIM * DIM;
        hfrag bw[2][4];
        #pragma unroll
        for (int nt = 0; nt < 2; ++nt)
            #pragma unroll
            for (int ks = 0; ks < 4; ++ks)
                bw[nt][ks] = *(const hfrag*)(Wt + (w * 32 + nt * 16 + col) * DIM + ks * 32 + quad * 8);

        f32x4 acc[2][2];
        #pragma unroll
        for (int mt = 0; mt < 2; ++mt)
            #pragma unroll
            for (int nt = 0; nt < 2; ++nt)
                acc[mt][nt] = f32x4{0.f, 0.f, 0.f, 0.f};

        #pragma unroll
        for (int mt = 0; mt < 2; ++mt)
            #pragma unroll
            for (int nt = 0; nt < 2; ++nt)
                #pragma unroll
                for (int ks = 0; ks < 4; ++ks)
                    acc[mt][nt] = __builtin_amdgcn_mfma_f32_16x16x32_f16(
                        bw[nt][ks], af[mt][ks], acc[mt][nt], 0, 0, 0);

        #pragma unroll
        for (int mt = 0; mt < 2; ++mt) {
            const int node = n0blk + mt * 16 + col;
            if (node >= N) continue;
            #pragma unroll
            for (int nt = 0; nt < 2; ++nt) {
                const int f0 = w * 32 + nt * 16 + quad * 4;
                if (m == 2) {
                    float4 o;
                    o.x = acc[mt][nt][0]; o.y = acc[mt][nt][1];
                    o.z = acc[mt][nt][2]; o.w = acc[mt][nt][3];
                    *(float4*)(skip + (size_t)node * DIM + f0) = o;
                } else {
                    float b0 = 0.f, b1v = 0.f, b2v = 0.f, b3v = 0.f;
                    if (m == 0) {
                        const float4 bb = *(const float4*)(bsrc + f0);
                        b0 = bb.x; b1v = bb.y; b2v = bb.z; b3v = bb.w;
                    }
                    uint2 o;
                    o.x = pkh(acc[mt][nt][0] + b0, acc[mt][nt][1] + b1v);
                    o.y = pkh(acc[mt][nt][2] + b2v, acc[mt][nt][3] + b3v);
                    unsigned short* dst = (m == 0) ? msg_src : msg_tgt;
                    *(uint2*)(dst + (size_t)node * DIM + f0) = o;
                }
            }
        }
    }
}

// ---------------------------------------------------------------------------
// K2: persistent, software-pipelined per-edge GEMM1 + gate (single dispatch).
// Both src AND tgt rows prefetched one tile ahead. fp8 e4m3 h2buf storage.
// ---------------------------------------------------------------------------
__global__ __launch_bounds__(256, 3) void edge_mlp_mfma(
    const int2* __restrict__ jip, int ntiles,
    const unsigned short* __restrict__ msg_src, const unsigned short* __restrict__ msg_tgt,
    const float* __restrict__ a0p,
    const unsigned short* __restrict__ W1t, const float* __restrict__ b1,
    const float* __restrict__ a1p,
    const float* __restrict__ w2g,
    unsigned char* __restrict__ h2buf,      // fp8 e4m3 [E,128], perm order
    float* __restrict__ gate)
{
    __shared__ unsigned short h1[2][64 * HSTR];
    __shared__ float gate_part[2][4][64];

    const int t = threadIdx.x;
    const float a0 = *a0p, a1 = *a1p;
    const h2v a02 = {(_Float16)a0, (_Float16)a0};
    const int w = t >> 6, lane = t & 63, col = lane & 15, quad = lane >> 4;
    const int o = t & 15, r0 = t >> 4;

    hfrag bw1[2][4];
    float4 b1q[2], wgq[2];
    #pragma unroll
    for (int nt = 0; nt < 2; ++nt) {
        const int n = w * 32 + nt * 16 + col;
        #pragma unroll
        for (int ks = 0; ks < 4; ++ks)
            bw1[nt][ks] = *(const hfrag*)(W1t + n * DIM + ks * 32 + quad * 8);
        const int nq = w * 32 + nt * 16 + quad * 4;
        b1q[nt] = *(const float4*)(b1 + nq);
        wgq[nt] = *(const float4*)(w2g + nq);
    }
    const float c2 = w2g[DIM];
    const int stride = gridDim.x;

    int tile = blockIdx.x;
    if (tile >= ntiles) return;

    int2 eA[4], eB[4];
    uint4 svA[4], svB[4], gvA[4], gvB[4];

    {
        const int p0 = tile * 64;
        #pragma unroll
        for (int i = 0; i < 4; ++i) eA[i] = jip[p0 + r0 + 16 * i];
        #pragma unroll
        for (int i = 0; i < 4; ++i) {
            svA[i] = *(const uint4*)(msg_src + (size_t)eA[i].x * DIM + o * 8);
            gvA[i] = *(const uint4*)(msg_tgt + (size_t)eA[i].y * DIM + o * 8);
        }
        const int tn = tile + stride;
        const int p1 = (tn < ntiles ? tn : tile) * 64;
        #pragma unroll
        for (int i = 0; i < 4; ++i) eB[i] = jip[p1 + r0 + 16 * i];
    }

    int buf = 0;
    int prev_p0 = -1;

    for (; tile < ntiles; tile += stride) {
        const int p0 = tile * 64;

        // 1. issue NEXT tile's src + tgt loads
        #pragma unroll
        for (int i = 0; i < 4; ++i) {
            svB[i] = *(const uint4*)(msg_src + (size_t)eB[i].x * DIM + o * 8);
            gvB[i] = *(const uint4*)(msg_tgt + (size_t)eB[i].y * DIM + o * 8);
        }

        // 2. combine current tile entirely from registers
        #pragma unroll
        for (int i = 0; i < 4; ++i) {
            uint4 hv;
            hv.x = prelu2_add(svA[i].x, gvA[i].x, a02);
            hv.y = prelu2_add(svA[i].y, gvA[i].y, a02);
            hv.z = prelu2_add(svA[i].z, gvA[i].z, a02);
            hv.w = prelu2_add(svA[i].w, gvA[i].w, a02);
            *(uint4*)(h1[buf] + (r0 + 16 * i) * HSTR + o * 8) = hv;
        }

        // 3. rotate idx; prefetch idx for tile+2*stride
        #pragma unroll
        for (int i = 0; i < 4; ++i) eA[i] = eB[i];
        {
            const int tnn = tile + 2 * stride;
            const int p2 = (tnn < ntiles ? tnn : tile) * 64;
            #pragma unroll
            for (int i = 0; i < 4; ++i) eB[i] = jip[p2 + r0 + 16 * i];
        }

        __syncthreads();

        // 3b. deferred gate write for PREVIOUS tile
        if (prev_p0 >= 0 && t < 64)
            gate[prev_p0 + t] = gate_part[1 - buf][0][t] + gate_part[1 - buf][1][t]
                              + gate_part[1 - buf][2][t] + gate_part[1 - buf][3][t] + c2;

        // 4. GEMM1 (transposed, fp16)
        f32x4 acc[4][2];
        #pragma unroll
        for (int mt = 0; mt < 4; ++mt)
            #pragma unroll
            for (int nt = 0; nt < 2; ++nt)
                acc[mt][nt] = f32x4{0.f, 0.f, 0.f, 0.f};

        #pragma unroll
        for (int mt = 0; mt < 4; ++mt) {
            hfrag af[4];
            #pragma unroll
            for (int ks = 0; ks < 4; ++ks)
                af[ks] = *(const hfrag*)(h1[buf] + (mt * 16 + col) * HSTR + ks * 32 + quad * 8);
            #pragma unroll
            for (int nt = 0; nt < 2; ++nt)
                #pragma unroll
                for (int ks = 0; ks < 4; ++ks)
                    acc[mt][nt] = __builtin_amdgcn_mfma_f32_16x16x32_f16(
                        bw1[nt][ks], af[ks], acc[mt][nt], 0, 0, 0);
        }

        // 5. epilogue: prelu -> h2buf (fp8), gate partials (fp32)
        #pragma unroll
        for (int mt = 0; mt < 4; ++mt) {
            const int m = mt * 16 + col;
            float g = 0.f;
            #pragma unroll
            for (int nt = 0; nt < 2; ++nt) {
                const int n0 = w * 32 + nt * 16 + quad * 4;
                const float p0v = prelu_f(acc[mt][nt][0] + b1q[nt].x, a1);
                const float p1v = prelu_f(acc[mt][nt][1] + b1q[nt].y, a1);
                const float p2v = prelu_f(acc[mt][nt][2] + b1q[nt].z, a1);
                const float p3v = prelu_f(acc[mt][nt][3] + b1q[nt].w, a1);
                int pk = __builtin_amdgcn_cvt_pk_fp8_f32(p0v, p1v, 0, false);
                pk = __builtin_amdgcn_cvt_pk_fp8_f32(p2v, p3v, pk, true);
                *(unsigned*)(h2buf + (size_t)(p0 + m) * DIM + n0) = (unsigned)pk;
                g += p0v * wgq[nt].x + p1v * wgq[nt].y + p2v * wgq[nt].z + p3v * wgq[nt].w;
            }
            g += __shfl_xor(g, 16);
            g += __shfl_xor(g, 32);
            if (quad == 0) gate_part[buf][w][m] = g;
        }

        // 6. rotate data registers
        #pragma unroll
        for (int i = 0; i < 4; ++i) { svA[i] = svB[i]; gvA[i] = gvB[i]; }
        prev_p0 = p0;
        buf ^= 1;
    }

    __syncthreads();
    if (t < 64)
        gate[prev_p0 + t] = gate_part[1 - buf][0][t] + gate_part[1 - buf][1][t]
                          + gate_part[1 - buf][2][t] + gate_part[1 - buf][3][t] + c2;
}

// ---------------------------------------------------------------------------
// K3: single-pass shift-free softmax aggregation over fp8 h2buf -> fp16 aggh2.
// ---------------------------------------------------------------------------
__global__ __launch_bounds__(256) void aggregate_h2_k(
    const int* __restrict__ rowptr,
    const float* __restrict__ gate, const unsigned char* __restrict__ h2buf,
    unsigned short* __restrict__ aggh2, int N)
{
    const int n = blockIdx.x * 4 + (threadIdx.x >> 6);
    const int lane = threadIdx.x & 63;
    if (n >= N) return;

    const int base = rowptr[n];
    const int deg = rowptr[n + 1] - base;
    const int grp = lane >> 4, sub = lane & 15;

    float acc[8] = {0.f, 0.f, 0.f, 0.f, 0.f, 0.f, 0.f, 0.f};
    float se = 0.f;
    for (int k = grp; k < deg; k += 4) {
        const float e = __expf(fminf(gate[base + k], 60.f));
        se += e;
        const uint2 mv = *(const uint2*)(h2buf + (size_t)(base + k) * DIM + sub * 8);
        const f32x2 f01 = __builtin_amdgcn_cvt_pk_f32_fp8(mv.x, false);
        const f32x2 f23 = __builtin_amdgcn_cvt_pk_f32_fp8(mv.x, true);
        const f32x2 f45 = __builtin_amdgcn_cvt_pk_f32_fp8(mv.y, false);
        const f32x2 f67 = __builtin_amdgcn_cvt_pk_f32_fp8(mv.y, true);
        acc[0] += e * f01.x; acc[1] += e * f01.y;
        acc[2] += e * f23.x; acc[3] += e * f23.y;
        acc[4] += e * f45.x; acc[5] += e * f45.y;
        acc[6] += e * f67.x; acc[7] += e * f67.y;
    }
    #pragma unroll
    for (int j = 0; j < 8; ++j) {
        acc[j] += __shfl_xor(acc[j], 16);
        acc[j] += __shfl_xor(acc[j], 32);
    }
    se += __shfl_xor(se, 16);
    se += __shfl_xor(se, 32);
    const float inv = 1.f / (se + 1e-16f);

    if (grp == 0) {
        uint4 ov;
        ov.x = pkh(acc[0] * inv, acc[1] * inv);
        ov.y = pkh(acc[2] * inv, acc[3] * inv);
        ov.z = pkh(acc[4] * inv, acc[5] * inv);
        ov.w = pkh(acc[6] * inv, acc[7] * inv);
        *(uint4*)(aggh2 + (size_t)n * DIM + sub * 8) = ov;
    }
}

// ---------------------------------------------------------------------------
// K4: out = LN(aggh2 @ W2 + b2 + skip) * gamma + beta, via fp16 MFMA.
// ---------------------------------------------------------------------------
__global__ __launch_bounds__(256) void node_out_k(
    const unsigned short* __restrict__ aggh2,
    const unsigned short* __restrict__ W2t, const float* __restrict__ b2,
    const float* __restrict__ skip,
    const float* __restrict__ gamma, const float* __restrict__ beta,
    float* __restrict__ out, int N)
{
    __shared__ unsigned short hh[64 * HSTR];
    __shared__ float ls1[4][4][16], ls2[4][4][16];

    const int t = threadIdx.x;
    const int n0blk = blockIdx.x * 64;
    const int w = t >> 6, lane = t & 63, col = lane & 15, quad = lane >> 4;

    hfrag bw2[2][4];
    float4 b2q[2];
    #pragma unroll
    for (int nt = 0; nt < 2; ++nt) {
        const int n = w * 32 + nt * 16 + col;
        #pragma unroll
        for (int ks = 0; ks < 4; ++ks)
            bw2[nt][ks] = *(const hfrag*)(W2t + n * DIM + ks * 32 + quad * 8);
        b2q[nt] = *(const float4*)(b2 + w * 32 + nt * 16 + quad * 4);
    }

    for (int k = t; k < 64 * 16; k += 256) {
        const int row = k >> 4, o = k & 15;
        uint4 v = make_uint4(0, 0, 0, 0);
        if (n0blk + row < N) v = *(const uint4*)(aggh2 + (size_t)(n0blk + row) * DIM + o * 8);
        *(uint4*)(hh + row * HSTR + o * 8) = v;
    }
    __syncthreads();

    f32x4 acc[4][2];
    #pragma unroll
    for (int mt = 0; mt < 4; ++mt)
        #pragma unroll
        for (int nt = 0; nt < 2; ++nt)
            acc[mt][nt] = f32x4{0.f, 0.f, 0.f, 0.f};

    #pragma unroll
    for (int mt = 0; mt < 4; ++mt) {
        hfrag af[4];
        #pragma unroll
        for (int ks = 0; ks < 4; ++ks)
            af[ks] = *(const hfrag*)(hh + (mt * 16 + col) * HSTR + ks * 32 + quad * 8);
        #pragma unroll
        for (int nt = 0; nt < 2; ++nt)
            #pragma unroll
            for (int ks = 0; ks < 4; ++ks)
                acc[mt][nt] = __builtin_amdgcn_mfma_f32_16x16x32_f16(
                    bw2[nt][ks], af[ks], acc[mt][nt], 0, 0, 0);
    }

    float v[4][2][4];
    #pragma unroll
    for (int mt = 0; mt < 4; ++mt) {
        const int node = n0blk + mt * 16 + col;
        float s1 = 0.f, s2 = 0.f;
        #pragma unroll
        for (int nt = 0; nt < 2; ++nt) {
            const int f0 = w * 32 + nt * 16 + quad * 4;
            float4 sk = make_float4(0.f, 0.f, 0.f, 0.f);
            if (node < N) sk = *(const float4*)(skip + (size_t)node * DIM + f0);
            v[mt][nt][0] = acc[mt][nt][0] + b2q[nt].x + sk.x;
            v[mt][nt][1] = acc[mt][nt][1] + b2q[nt].y + sk.y;
            v[mt][nt][2] = acc[mt][nt][2] + b2q[nt].z + sk.z;
            v[mt][nt][3] = acc[mt][nt][3] + b2q[nt].w + sk.w;
            #pragma unroll
            for (int r = 0; r < 4; ++r) {
                s1 += v[mt][nt][r];
                s2 += v[mt][nt][r] * v[mt][nt][r];
            }
        }
        s1 += __shfl_xor(s1, 16); s1 += __shfl_xor(s1, 32);
        s2 += __shfl_xor(s2, 16); s2 += __shfl_xor(s2, 32);
        if (quad == 0) { ls1[w][mt][col] = s1; ls2[w][mt][col] = s2; }
    }
    __syncthreads();

    #pragma unroll
    for (int mt = 0; mt < 4; ++mt) {
        const int node = n0blk + mt * 16 + col;
        if (node >= N) continue;
        const float sum = ls1[0][mt][col] + ls1[1][mt][col] + ls1[2][mt][col] + ls1[3][mt][col];
        const float sq  = ls2[0][mt][col] + ls2[1][mt][col] + ls2[2][mt][col] + ls2[3][mt][col];
        const float mu = sum * (1.f / 128.f);
        const float var = sq * (1.f / 128.f) - mu * mu;
        const float rs = rsqrtf(var + 1e-5f);
        #pragma unroll
        for (int nt = 0; nt < 2; ++nt) {
            const int f0 = w * 32 + nt * 16 + quad * 4;
            const float4 gm = *(const float4*)(gamma + f0);
            const float4 bt = *(const float4*)(beta + f0);
            float4 ov;
            ov.x = (v[mt][nt][0] - mu) * rs * gm.x + bt.x;
            ov.y = (v[mt][nt][1] - mu) * rs * gm.y + bt.y;
            ov.z = (v[mt][nt][2] - mu) * rs * gm.z + bt.z;
            ov.w = (v[mt][nt][3] - mu) * rs * gm.w + bt.w;
            *(float4*)(out + (size_t)node * DIM + f0) = ov;
        }
    }
}

// ---------------------------------------------------------------------------
extern "C" void kernel_launch(void* const* d_in, const int* in_sizes, int n_in,
                              void* d_out, int out_size, void* d_ws, size_t ws_size,
                              hipStream_t stream)
{
    const float* x     = (const float*)d_in[0];
    const int*   eidx  = (const int*)d_in[1];
    const float* Wsrc  = (const float*)d_in[2];
    const float* bsrc  = (const float*)d_in[3];
    const float* Wtgt  = (const float*)d_in[4];
    const float* Wskip = (const float*)d_in[5];
    const float* a0    = (const float*)d_in[6];
    const float* W1    = (const float*)d_in[7];
    const float* b1    = (const float*)d_in[8];
    const float* a1    = (const float*)d_in[9];
    const float* W2    = (const float*)d_in[10];
    const float* b2    = (const float*)d_in[11];
    const float* Wg    = (const float*)d_in[12];
    const float* gamma = (const float*)d_in[13];
    const float* beta  = (const float*)d_in[14];

    const int N = in_sizes[0] / DIM;      // 20000
    const int E = in_sizes[1] / 2;        // 640000
    const int Npad = ((N + 63) / 64) * 64;
    float* out = (float*)d_out;

    char* ws = (char*)d_ws;
    size_t off = 0;
    auto alloc = [&](size_t bytes) -> void* {
        void* p = ws + off;
        off += (bytes + 255) & ~(size_t)255;
        return p;
    };
    unsigned short* msg_src = (unsigned short*)alloc((size_t)N * DIM * 2);
    unsigned short* msg_tgt = (unsigned short*)alloc((size_t)N * DIM * 2);
    float*          skip    = (float*)alloc((size_t)N * DIM * 4);
    float*          gate    = (float*)alloc((size_t)E * 4);
    int*            deg     = (int*)alloc((size_t)N * 4);
    int*            rowptr  = (int*)alloc((size_t)(N + 1) * 4);
    int*            rank    = (int*)alloc((size_t)E * 4);
    int2*           jip     = (int2*)alloc((size_t)E * 8);
    unsigned short* Wall    = (unsigned short*)alloc((size_t)5 * DIM * DIM * 2);
    float*          w2g     = (float*)alloc((size_t)(DIM + 1) * 4);
    unsigned short* aggh2   = (unsigned short*)alloc((size_t)Npad * DIM * 2);
    unsigned char*  h2buf   = (unsigned char*)alloc((size_t)E * DIM);
    (void)ws_size; (void)n_in; (void)out_size;

    (void)hipMemsetAsync(deg, 0, (size_t)N * 4, stream);

    const int nhist = (E + 255) / 256;
    prep_hist_k<<<nhist + (5 * DIM * DIM) / 256 + 1, 256, 0, stream>>>(
        Wsrc, Wtgt, Wskip, W1, W2, b2, Wg, Wall, w2g, eidx, E, deg, rank);

    scan_k<<<1, 256, 0, stream>>>(deg, rowptr, N);

    const int nscatter = (E + 255) / 256;
    const int nnode = (N + 31) / 32;
    scatter_node_k<<<nscatter + nnode, 256, 0, stream>>>(
        eidx, E, rowptr, rank, jip, nscatter,
        x, Wall, bsrc, msg_src, msg_tgt, skip, N);

    const int ntiles = E / 64;
    const int egrid = ntiles < 1024 ? ntiles : 1024;
    edge_mlp_mfma<<<egrid, 256, 0, stream>>>(jip, ntiles, msg_src, msg_tgt, a0,
                                             Wall + 3 * DIM * DIM, b1, a1,
                                             w2g, h2buf, gate);

    aggregate_h2_k<<<(N + 3) / 4, 256, 0, stream>>>(rowptr, gate, h2buf, aggh2, N);

    node_out_k<<<Npad / 64, 256, 0, stream>>>(aggh2, Wall + 4 * DIM * DIM, b2, skip,
                                              gamma, beta, out, N);
}